// Round 1
// 1248.735 us; speedup vs baseline: 1.0147x; 1.0147x over previous
//
#include <hip/hip_runtime.h>
#include <hip/hip_bf16.h>

typedef unsigned short u16;
typedef __attribute__((ext_vector_type(8))) short short8;   // 8 bf16 = 4 VGPRs (MFMA A/B frag)
typedef __attribute__((ext_vector_type(4))) float f32x4;    // MFMA C/D frag
typedef __attribute__((ext_vector_type(4))) unsigned short us4;

#define MFMA16(A,B,C) __builtin_amdgcn_mfma_f32_16x16x32_bf16((A),(B),(C),0,0,0)

__device__ __forceinline__ float bf2f(u16 u){ return __uint_as_float(((unsigned)u)<<16); }
__device__ __forceinline__ u16 f2bf(float f){
  unsigned x = __float_as_uint(f);
  return (u16)((x + 0x7FFFu + ((x>>16)&1u)) >> 16);   // RNE
}
__device__ __forceinline__ float sigm(float x){ return __fdividef(1.f, 1.f + __expf(-x)); }
__device__ __forceinline__ float tanh_(float x){ return __fdividef(2.f, 1.f + __expf(-2.f*x)) - 1.f; }
__device__ __forceinline__ short8 ldg8(const u16* p){ return *(const short8*)p; }

// ---------------------------------------------------------------------------
// K0: dtype-agnostic input conversion (fp32 or bf16 source -> bf16 scratch).
// Blocks 0..19 convert weight arrays 1..20; blocks 20+ grid-stride over x.
// ---------------------------------------------------------------------------
struct CvtArgs {
  const void* src[21];
  u16* dst[21];
  int n[21];
};

__global__ __launch_bounds__(256,1) void k_cvt(CvtArgs a)
{
  const u16* d = (const u16*)a.src[0];
  int imp = 0, pl = 0;
#pragma unroll
  for (int i = 0; i < 128; i += 2){
    u16 u = d[i]; int e = (u >> 7) & 0xFF;
    if (u){ if (e >= 104 && e <= 134) pl++; else imp++; }
  }
  bool isf32 = imp > pl;

  int which, i0, stride;
  if (blockIdx.x < 20){ which = blockIdx.x + 1; i0 = threadIdx.x; stride = 256; }
  else { which = 0; i0 = (blockIdx.x - 20)*256 + threadIdx.x; stride = (gridDim.x - 20)*256; }
  int n = a.n[which];
  u16* dst = a.dst[which];
  if (isf32){
    const float* s = (const float*)a.src[which];
    for (int i = i0; i < n; i += stride) dst[i] = f2bf(s[i]);
  } else {
    const u16* s = (const u16*)a.src[which];
    for (int i = i0; i < n; i += stride) dst[i] = s[i];
  }
}

// ---------------------------------------------------------------------------
// K1: xb[b,c,t,f] (bf16) -> xp[(b*400+t), f, c] (bf16). One block per (b,t).
// ---------------------------------------------------------------------------
__global__ __launch_bounds__(256,1) void k_transpose(const u16* __restrict__ x, u16* __restrict__ xp)
{
  int nb = blockIdx.x; int b = nb/400, t = nb - b*400;
  int tid = threadIdx.x;
  __shared__ u16 tl[64*66];
  int f0 = (tid & 31) * 2;
#pragma unroll
  for (int p = 0; p < 8; p++){
    int c = p*8 + (tid>>5);
    unsigned u = *(const unsigned*)(x + (((size_t)b*64 + c)*400 + t)*64 + f0);
    *(unsigned*)(tl + c*66 + f0) = u;
  }
  __syncthreads();
  int c0 = (tid & 31) * 2;
  u16* dst = xp + (size_t)nb*4096;
#pragma unroll
  for (int p = 0; p < 8; p++){
    int f = p*8 + (tid>>5);
    unsigned u = (unsigned)tl[c0*66 + f] | ((unsigned)tl[(c0+1)*66 + f] << 16);
    *(unsigned*)(dst + f*64 + c0) = u;
  }
}

// ---------------------------------------------------------------------------
// K2: intra bidirectional GRU. 1 wave = 16 sequences, 64 steps, gx fused.
// grid = 800 (400 tiles x 2 dirs). MFMA 16x16x32 bf16.
// A[m=lane&15][k=(lane>>4)*8+j], B[k=(lane>>4)*8+j][n=lane&15],
// D: col=lane&15, row=(lane>>4)*4+reg.
// ---------------------------------------------------------------------------
__global__ __launch_bounds__(64,1) void k_intra(
    const u16* __restrict__ xp,
    const u16* __restrict__ Wih_f, const u16* __restrict__ Whh_f,
    const u16* __restrict__ bih_f, const u16* __restrict__ bhh_f,
    const u16* __restrict__ Wih_b, const u16* __restrict__ Whh_b,
    const u16* __restrict__ bih_b, const u16* __restrict__ bhh_b,
    u16* __restrict__ yfo, u16* __restrict__ ybo)
{
  int blk = blockIdx.x;
  int dir = blk >= 400;
  int tile = dir ? blk - 400 : blk;
  int n0 = tile * 16;
  const u16* Wih = dir ? Wih_b : Wih_f;
  const u16* Whh = dir ? Whh_b : Whh_f;
  const u16* bih = dir ? bih_b : bih_f;
  const u16* bhh = dir ? bhh_b : bhh_f;
  u16* yo = dir ? ybo : yfo;

  int lane = threadIdx.x;
  int m = lane & 15, q = lane >> 4;

  short8 wrx[4][2], wzx[4][2], wnx[4][2], wrh[4][2], wzh[4][2], wnh[4][2];
#pragma unroll
  for (int nt = 0; nt < 4; nt++){
#pragma unroll
    for (int kc = 0; kc < 2; kc++){
      int co = kc*32 + q*8;
      wrx[nt][kc] = ldg8(Wih + (      nt*16 + m)*64 + co);
      wzx[nt][kc] = ldg8(Wih + ( 64 + nt*16 + m)*64 + co);
      wnx[nt][kc] = ldg8(Wih + (128 + nt*16 + m)*64 + co);
      wrh[nt][kc] = ldg8(Whh + (      nt*16 + m)*64 + co);
      wzh[nt][kc] = ldg8(Whh + ( 64 + nt*16 + m)*64 + co);
      wnh[nt][kc] = ldg8(Whh + (128 + nt*16 + m)*64 + co);
    }
  }
  float br[4], bz[4], bnx_[4], bnh_[4];
#pragma unroll
  for (int nt = 0; nt < 4; nt++){
    int u = nt*16 + m;
    br[nt]   = bf2f(bih[u])     + bf2f(bhh[u]);
    bz[nt]   = bf2f(bih[64+u])  + bf2f(bhh[64+u]);
    bnx_[nt] = bf2f(bih[128+u]);
    bnh_[nt] = bf2f(bhh[128+u]);
  }

  __shared__ u16 hl[16*72];
  float h[4][4];
#pragma unroll
  for (int nt=0;nt<4;nt++){
#pragma unroll
    for (int p=0;p<4;p++) h[nt][p] = 0.f;
  }
  short8 hf0 = {0,0,0,0,0,0,0,0}, hf1 = {0,0,0,0,0,0,0,0};
  int f = dir ? 63 : 0, df = dir ? -1 : 1;
  short8 xf0 = ldg8(xp + ((size_t)(n0+m)*64 + f)*64 + q*8);
  short8 xf1 = ldg8(xp + ((size_t)(n0+m)*64 + f)*64 + 32 + q*8);

  for (int s = 0; s < 64; s++){
    f32x4 ar[4], az[4], anx[4], anh[4];
#pragma unroll
    for (int nt=0;nt<4;nt++){
      ar[nt]  = (f32x4){br[nt],br[nt],br[nt],br[nt]};
      az[nt]  = (f32x4){bz[nt],bz[nt],bz[nt],bz[nt]};
      anx[nt] = (f32x4){bnx_[nt],bnx_[nt],bnx_[nt],bnx_[nt]};
      anh[nt] = (f32x4){bnh_[nt],bnh_[nt],bnh_[nt],bnh_[nt]};
    }
#pragma unroll
    for (int nt=0;nt<4;nt++){
      ar[nt]  = MFMA16(hf0, wrh[nt][0], ar[nt]);
      ar[nt]  = MFMA16(hf1, wrh[nt][1], ar[nt]);
      ar[nt]  = MFMA16(xf0, wrx[nt][0], ar[nt]);
      ar[nt]  = MFMA16(xf1, wrx[nt][1], ar[nt]);
      az[nt]  = MFMA16(hf0, wzh[nt][0], az[nt]);
      az[nt]  = MFMA16(hf1, wzh[nt][1], az[nt]);
      az[nt]  = MFMA16(xf0, wzx[nt][0], az[nt]);
      az[nt]  = MFMA16(xf1, wzx[nt][1], az[nt]);
      anx[nt] = MFMA16(xf0, wnx[nt][0], anx[nt]);
      anx[nt] = MFMA16(xf1, wnx[nt][1], anx[nt]);
      anh[nt] = MFMA16(hf0, wnh[nt][0], anh[nt]);
      anh[nt] = MFMA16(hf1, wnh[nt][1], anh[nt]);
    }
    int fn = f + df;
    if (s < 63){
      xf0 = ldg8(xp + ((size_t)(n0+m)*64 + fn)*64 + q*8);
      xf1 = ldg8(xp + ((size_t)(n0+m)*64 + fn)*64 + 32 + q*8);
    }
#pragma unroll
    for (int nt=0;nt<4;nt++){
#pragma unroll
      for (int p=0;p<4;p++){
        float r  = sigm(ar[nt][p]);
        float z  = sigm(az[nt][p]);
        float n  = tanh_(anx[nt][p] + r*anh[nt][p]);
        float hn = n + z*(h[nt][p] - n);
        h[nt][p] = hn;
        hl[(q*4+p)*72 + nt*16 + m] = f2bf(hn);
      }
    }
    __threadfence_block();   // order u16 gate-writes before vector LDS reads
    int sl = lane >> 2, ch = lane & 3;
    short8 y0 = *(const short8*)(hl + sl*72 + ch*16);
    short8 y1 = *(const short8*)(hl + sl*72 + ch*16 + 8);
    *(short8*)(yo + ((size_t)(n0+sl)*64 + f)*64 + ch*16)     = y0;
    *(short8*)(yo + ((size_t)(n0+sl)*64 + f)*64 + ch*16 + 8) = y1;
    hf0 = *(const short8*)(hl + m*72 + q*8);
    hf1 = *(const short8*)(hl + m*72 + 32 + q*8);
    __threadfence_block();   // order reads before next iteration's writes
    f = fn;
  }
}

// ---------------------------------------------------------------------------
// K3: intra FC(128->64) + LayerNorm(f,c) + residual. 1 block per (b,t), 4 waves.
// ---------------------------------------------------------------------------
__global__ __launch_bounds__(256,1) void k_ifc(
  const u16* __restrict__ yf, const u16* __restrict__ yb,
  const u16* __restrict__ fcw, const u16* __restrict__ fcb,
  const u16* __restrict__ lng, const u16* __restrict__ lnb,
  const u16* __restrict__ xp, u16* __restrict__ lnI, u16* __restrict__ iout)
{
  int nb = blockIdx.x; int b = nb/400, t = nb - b*400;
  int tid = threadIdx.x; int wv = tid>>6; int lane = tid&63;
  int m = lane&15, q = lane>>4;
  int rb = nb*64 + wv*16;
  short8 a0 = ldg8(yf + (size_t)(rb+m)*64 + q*8);
  short8 a1 = ldg8(yf + (size_t)(rb+m)*64 + 32 + q*8);
  short8 a2 = ldg8(yb + (size_t)(rb+m)*64 + q*8);
  short8 a3 = ldg8(yb + (size_t)(rb+m)*64 + 32 + q*8);
  f32x4 acc[4];
#pragma unroll
  for (int nt=0;nt<4;nt++){
    float bias = bf2f(fcb[nt*16+m]);
    acc[nt] = (f32x4){bias,bias,bias,bias};
    acc[nt] = MFMA16(a0, ldg8(fcw + (nt*16+m)*128 +      q*8), acc[nt]);
    acc[nt] = MFMA16(a1, ldg8(fcw + (nt*16+m)*128 + 32 + q*8), acc[nt]);
    acc[nt] = MFMA16(a2, ldg8(fcw + (nt*16+m)*128 + 64 + q*8), acc[nt]);
    acc[nt] = MFMA16(a3, ldg8(fcw + (nt*16+m)*128 + 96 + q*8), acc[nt]);
  }
  float s=0.f, s2=0.f;
#pragma unroll
  for (int nt=0;nt<4;nt++){
#pragma unroll
    for (int p=0;p<4;p++){ float v=acc[nt][p]; s+=v; s2+=v*v; }
  }
  for (int o=32;o>0;o>>=1){ s += __shfl_down(s,o); s2 += __shfl_down(s2,o); }
  __shared__ float red[8];
  if (lane==0){ red[wv]=s; red[4+wv]=s2; }
  __syncthreads();
  float S  = red[0]+red[1]+red[2]+red[3];
  float S2 = red[4]+red[5]+red[6]+red[7];
  float mu = S*(1.f/4096.f);
  float rstd = rsqrtf(S2*(1.f/4096.f) - mu*mu + 1e-8f);
#pragma unroll
  for (int nt=0;nt<4;nt++){
#pragma unroll
    for (int p=0;p<4;p++){
      int row = wv*16 + q*4 + p;   // f
      int col = nt*16 + m;         // c
      float v = (acc[nt][p]-mu)*rstd;
      v = v*bf2f(lng[row*64+col]) + bf2f(lnb[row*64+col]);
      lnI[(size_t)nb*4096 + row*64 + col] = f2bf(v);
      float xv = bf2f(xp[(size_t)nb*4096 + row*64 + col]);
      iout[(((size_t)b*64 + row)*400 + t)*64 + col] = f2bf(v + xv);
    }
  }
}

// ---------------------------------------------------------------------------
// K4: PE gx GEMM. rows = (b,f,t) over intra_out[b,f,t,c]; grouped Wih.
// ---------------------------------------------------------------------------
__global__ __launch_bounds__(64,1) void k_gx(const u16* __restrict__ io,
   const u16* __restrict__ pw, const u16* __restrict__ pb, u16* __restrict__ gx)
{
  int r0 = blockIdx.x * 16;
  int seq = r0 / 400;
  int g = (seq & 63) >> 3;
  int lane = threadIdx.x; int m = lane&15, q = lane>>4;
  short8 a0 = ldg8(io + (size_t)(r0+m)*64 + q*8);
  short8 a1 = ldg8(io + (size_t)(r0+m)*64 + 32 + q*8);
  const u16* W = pw + g*12288;
#pragma unroll
  for (int nt=0; nt<12; nt++){
    float bias = bf2f(pb[g*192 + nt*16 + m]);
    f32x4 acc = (f32x4){bias,bias,bias,bias};
    acc = MFMA16(a0, ldg8(W + (nt*16+m)*64 + q*8), acc);
    acc = MFMA16(a1, ldg8(W + (nt*16+m)*64 + 32 + q*8), acc);
#pragma unroll
    for (int p=0;p<4;p++)
      gx[(size_t)(r0 + q*4 + p)*192 + nt*16 + m] = f2bf(acc[p]);
  }
}

// ---------------------------------------------------------------------------
// K5: PE recurrence, MFMA-batched (replaces the scalar-readlane version whose
// 192 fp32 weights/lane could not fit in 108 VGPRs -> scratch thrash).
// 64 tiles of 16 same-group sequences; 1 block = 4 waves per tile.
// Wave w owns gate triple {r,z,n} for units w*16..w*16+15 (12 MFMAs/step with
// hi/lo bf16-compensated h so the recurrence stays fp32-equivalent).
// Elementwise (6 transcendentals per h -> the real floor) is spread 4-ways:
// 4 h values per lane per step. One __syncthreads per step; double-buffered
// LDS h; gx ([seq][t][192], L3-resident) prefetched one step ahead.
// ---------------------------------------------------------------------------
__global__ __launch_bounds__(256,1) void k_pe(const u16* __restrict__ gx,
  const u16* __restrict__ whh, const u16* __restrict__ bhh, u16* __restrict__ ype)
{
  int tile = blockIdx.x;          // 0..63
  int g = tile >> 3, tl = tile & 7;
  int tid = threadIdx.x;
  int w = tid >> 6;               // wave 0..3: gate-unit triple
  int lane = tid & 63;
  int m = lane & 15, q = lane >> 4;

  // B-frags: Whh^T for nt tiles {w (r), w+4 (z), w+8 (n)}, kc 0/1.
  const u16* W = whh + g*12288;
  short8 wr[2], wz[2], wn[2];
#pragma unroll
  for (int kc = 0; kc < 2; kc++){
    int co = kc*32 + q*8;
    wr[kc] = ldg8(W + (((size_t)w    *16 + m))*64 + co);
    wz[kc] = ldg8(W + (((size_t)(w+4)*16 + m))*64 + co);
    wn[kc] = ldg8(W + (((size_t)(w+8)*16 + m))*64 + co);
  }
  float brh = bf2f(bhh[g*192 +       w*16 + m]);
  float bzh = bf2f(bhh[g*192 + 64  + w*16 + m]);
  float bnh = bf2f(bhh[g*192 + 128 + w*16 + m]);

  // gx pointers for the 4 sequences this lane's D-rows cover (seq = q*4+p).
  // tile-local sl -> global seq: sidx = tl*16+sl; seq = (sidx>>3)*64 + g*8 + (sidx&7)
  const u16* bp[4];
#pragma unroll
  for (int p = 0; p < 4; p++){
    int sl = q*4 + p;
    int sidx = tl*16 + sl;
    int seqg = (sidx >> 3)*64 + g*8 + (sidx & 7);
    bp[p] = gx + (size_t)seqg*400*192 + w*16 + m;
  }

  // ype store mapping: wave w stores seqs w*4..w*4+3; lane -> (seq, 4-unit chunk)
  int sls = w*4 + (lane >> 4);
  int sidxs = tl*16 + sls;
  int seqs_ = (sidxs >> 3)*64 + g*8 + (sidxs & 7);
  int u0 = (lane & 15)*4;
  u16* yp = ype + (size_t)seqs_*400*64 + u0;
  int hlr = sls*72 + u0;

  __shared__ u16 hl[2][2][16*72];   // [buf][hi/lo][seq*72 + unit]

  float hprev[4] = {0.f, 0.f, 0.f, 0.f};
  short8 hA0 = {0,0,0,0,0,0,0,0}, hA1 = {0,0,0,0,0,0,0,0};  // h hi frags
  short8 hB0 = {0,0,0,0,0,0,0,0}, hB1 = {0,0,0,0,0,0,0,0};  // h lo frags

  u16 gr[4], gz[4], gn[4];
#pragma unroll
  for (int p = 0; p < 4; p++){ gr[p] = bp[p][0]; gz[p] = bp[p][64]; gn[p] = bp[p][128]; }

  int cur = 0;
  for (int t = 0; t < 400; t++){
    f32x4 ar, az, anh;
    float gnf[4];
#pragma unroll
    for (int p = 0; p < 4; p++){
      ar[p]  = bf2f(gr[p]) + brh;   // gx already contains bih
      az[p]  = bf2f(gz[p]) + bzh;
      anh[p] = bnh;                 // n-gate: keep x-part separate (r gates it)
      gnf[p] = bf2f(gn[p]);
    }
    // prefetch next step's gx (latency hidden under MFMA + elementwise)
    if (t < 399){
#pragma unroll
      for (int p = 0; p < 4; p++){
        bp[p] += 192;
        gr[p] = bp[p][0]; gz[p] = bp[p][64]; gn[p] = bp[p][128];
      }
    }
    ar  = MFMA16(hA0, wr[0], ar);  ar  = MFMA16(hA1, wr[1], ar);
    ar  = MFMA16(hB0, wr[0], ar);  ar  = MFMA16(hB1, wr[1], ar);
    az  = MFMA16(hA0, wz[0], az);  az  = MFMA16(hA1, wz[1], az);
    az  = MFMA16(hB0, wz[0], az);  az  = MFMA16(hB1, wz[1], az);
    anh = MFMA16(hA0, wn[0], anh); anh = MFMA16(hA1, wn[1], anh);
    anh = MFMA16(hB0, wn[0], anh); anh = MFMA16(hB1, wn[1], anh);
#pragma unroll
    for (int p = 0; p < 4; p++){
      float r  = sigm(ar[p]);
      float z  = sigm(az[p]);
      float n  = tanh_(gnf[p] + r*anh[p]);
      float hn = n + z*(hprev[p] - n);
      hprev[p] = hn;
      u16 hi = f2bf(hn);
      int off = (q*4 + p)*72 + w*16 + m;
      hl[cur][0][off] = hi;
      hl[cur][1][off] = f2bf(hn - bf2f(hi));   // residual keeps recurrence ~fp32
    }
    __syncthreads();
    // output h_t (hi part) for this wave's 4 seqs: 16 lanes x 8B = 128B/seq
    *(us4*)yp = *(const us4*)&hl[cur][0][hlr];
    yp += 64;
    // reload full h as next step's A-frags
    hA0 = *(const short8*)&hl[cur][0][m*72 + q*8];
    hA1 = *(const short8*)&hl[cur][0][m*72 + 32 + q*8];
    hB0 = *(const short8*)&hl[cur][1][m*72 + q*8];
    hB1 = *(const short8*)&hl[cur][1][m*72 + 32 + q*8];
    cur ^= 1;
  }
}

// ---------------------------------------------------------------------------
// K6: PE FC (grouped 64->64). Writes fcpe bf16 in [b,t,f,o] for LN.
// ---------------------------------------------------------------------------
__global__ __launch_bounds__(64,1) void k_pefc(const u16* __restrict__ ype,
  const u16* __restrict__ fw, const u16* __restrict__ fb, u16* __restrict__ fcpe)
{
  int r0 = blockIdx.x * 16;
  int seq = r0 / 400;
  int g = (seq & 63) >> 3;
  int b = seq >> 6, f = seq & 63;
  int tb = r0 - seq*400;
  int lane = threadIdx.x; int m = lane&15, q = lane>>4;
  short8 a0 = ldg8(ype + (size_t)(r0+m)*64 + q*8);
  short8 a1 = ldg8(ype + (size_t)(r0+m)*64 + 32 + q*8);
  const u16* W = fw + g*4096;
#pragma unroll
  for (int nt=0;nt<4;nt++){
    float bias = bf2f(fb[g*64 + nt*16 + m]);
    f32x4 acc = (f32x4){bias,bias,bias,bias};
    acc = MFMA16(a0, ldg8(W + (nt*16+m)*64 + q*8), acc);
    acc = MFMA16(a1, ldg8(W + (nt*16+m)*64 + 32 + q*8), acc);
#pragma unroll
    for (int p=0;p<4;p++){
      int t = tb + q*4 + p;
      fcpe[(((size_t)b*400 + t)*64 + f)*64 + nt*16 + m] = f2bf(acc[p]);
    }
  }
}

// ---------------------------------------------------------------------------
// K7: final LN(PE) + add intra(LN) + transpose to out[b,c,t,f] (FP32 —
// the reference's output dtype).
// ---------------------------------------------------------------------------
__global__ __launch_bounds__(256,1) void k_final(const u16* __restrict__ fcpe,
  const u16* __restrict__ lnI, const u16* __restrict__ g_, const u16* __restrict__ b_,
  float* __restrict__ out)
{
  int nb = blockIdx.x; int b = nb/400, t = nb - b*400;
  int tid = threadIdx.x;
  const u16* src = fcpe + (size_t)nb*4096 + tid*16;
  short8 v0 = ldg8(src), v1 = ldg8(src + 8);
  float v[16];
#pragma unroll
  for (int i=0;i<8;i++){ v[i] = bf2f((u16)v0[i]); v[8+i] = bf2f((u16)v1[i]); }
  float s=0.f, s2=0.f;
#pragma unroll
  for (int i=0;i<16;i++){ s+=v[i]; s2+=v[i]*v[i]; }
  int lane = tid&63, wv = tid>>6;
  for (int o=32;o>0;o>>=1){ s += __shfl_down(s,o); s2 += __shfl_down(s2,o); }
  __shared__ float red[8];
  __shared__ float tr[64*68];
  if (lane==0){ red[wv]=s; red[4+wv]=s2; }
  __syncthreads();
  float S  = red[0]+red[1]+red[2]+red[3];
  float S2 = red[4]+red[5]+red[6]+red[7];
  float mu = S*(1.f/4096.f);
  float rstd = rsqrtf(S2*(1.f/4096.f) - mu*mu + 1e-8f);
  int ff = tid>>2; int c0 = (tid&3)*16;
  const u16* lp = lnI + (size_t)nb*4096 + tid*16;
  short8 l0 = ldg8(lp), l1 = ldg8(lp + 8);
#pragma unroll
  for (int i=0;i<16;i++){
    int c = c0 + i;
    float x = (v[i]-mu)*rstd*bf2f(g_[ff*64+c]) + bf2f(b_[ff*64+c]);
    x += (i<8) ? bf2f((u16)l0[i]) : bf2f((u16)l1[i-8]);
    tr[c*68 + ff] = x;
  }
  __syncthreads();
  int cc = tid>>2, fc = (tid&3)*16;
  float* dst = out + (((size_t)b*64 + cc)*400 + t)*64 + fc;
#pragma unroll
  for (int i=0;i<16;i+=4){
    *(f32x4*)(dst + i) = *(const f32x4*)(tr + cc*68 + fc + i);
  }
}

// ---------------------------------------------------------------------------
// Workspace (peak 262,759,040 B ~ 250.6 MiB):
//   [0        , 52428800 )  xp    (k_transpose -> k_ifc); later gx; later fcpe
//   [52428800 , 104857600)  xb    (k_cvt -> k_transpose); later yf (k_intra -> k_ifc); later gx
//   [104857600, 157286400)  yb    (k_intra -> k_ifc); later gx
//   [157286400, 209715200)  lnI   (k_ifc -> k_final)
//   [209715200, 262144000)  iout  (k_ifc -> k_gx); later ype (k_pe -> k_pefc)
//   [262144000, 262759040)  wb    converted weights (k_cvt -> end)
// ---------------------------------------------------------------------------
extern "C" void kernel_launch(void* const* d_in, const int* in_sizes, int n_in,
                              void* d_out, int out_size, void* d_ws, size_t ws_size,
                              hipStream_t stream)
{
  (void)in_sizes; (void)n_in; (void)out_size; (void)ws_size;

  char* ws = (char*)d_ws;
  u16* xp   = (u16*)(ws + 0ull);
  u16* xb   = (u16*)(ws + 52428800ull);
  u16* yf   = (u16*)(ws + 52428800ull);
  u16* yb   = (u16*)(ws + 104857600ull);
  u16* lnI  = (u16*)(ws + 157286400ull);
  u16* iout = (u16*)(ws + 209715200ull);
  u16* gx   = (u16*)(ws + 0ull);
  u16* ype  = (u16*)(ws + 209715200ull);
  u16* fcpe = (u16*)(ws + 0ull);
  u16* wb   = (u16*)(ws + 262144000ull);

  static const int wn[21] = {26214400,
    12288,12288,192,192, 12288,12288,192,192,
    8192,64,4096,4096, 98304,98304,1536,1536, 32768,512,4096,4096};
  int woff[21]; woff[0] = 0;
  int acc = 0;
  for (int i = 1; i <= 20; i++){ woff[i] = acc; acc += wn[i]; }

  CvtArgs ca;
  for (int i = 0; i < 21; i++){
    ca.src[i] = d_in[i];
    ca.n[i] = wn[i];
    ca.dst[i] = (i == 0) ? xb : (wb + woff[i]);
  }

  const u16* iWihf = wb + woff[1];
  const u16* iWhhf = wb + woff[2];
  const u16* ibihf = wb + woff[3];
  const u16* ibhhf = wb + woff[4];
  const u16* iWihb = wb + woff[5];
  const u16* iWhhb = wb + woff[6];
  const u16* ibihb = wb + woff[7];
  const u16* ibhhb = wb + woff[8];
  const u16* fcW   = wb + woff[9];
  const u16* fcB   = wb + woff[10];
  const u16* ilng  = wb + woff[11];
  const u16* ilnb  = wb + woff[12];
  const u16* peWih = wb + woff[13];
  const u16* peWhh = wb + woff[14];
  const u16* pebih = wb + woff[15];
  const u16* pebhh = wb + woff[16];
  const u16* pefcW = wb + woff[17];
  const u16* pefcb = wb + woff[18];
  const u16* pelng = wb + woff[19];
  const u16* pelnb = wb + woff[20];

  k_cvt<<<dim3(2068), dim3(256), 0, stream>>>(ca);
  k_transpose<<<dim3(6400), dim3(256), 0, stream>>>(xb, xp);
  k_intra<<<dim3(800), dim3(64), 0, stream>>>(xp, iWihf, iWhhf, ibihf, ibhhf,
                                              iWihb, iWhhb, ibihb, ibhhb, yf, yb);
  k_ifc<<<dim3(6400), dim3(256), 0, stream>>>(yf, yb, fcW, fcB, ilng, ilnb, xp, lnI, iout);
  k_gx<<<dim3(25600), dim3(64), 0, stream>>>(iout, peWih, pebih, gx);
  k_pe<<<dim3(64), dim3(256), 0, stream>>>(gx, peWhh, pebhh, ype);
  k_pefc<<<dim3(25600), dim3(64), 0, stream>>>(ype, pefcW, pefcb, fcpe);
  k_final<<<dim3(6400), dim3(256), 0, stream>>>(fcpe, lnI, pelng, pelnb, (float*)d_out);
}